// Round 1
// baseline (2410.162 us; speedup 1.0000x reference)
//
#include <hip/hip_runtime.h>
#include <hip/hip_bf16.h>
#include <math.h>

#define T_STEPS 256
#define BATCH   256
#define FDIM    128
#define HDIM    384
#define LLEV    3
#define KWIN    10
#define GDIM    1542
#define SDIM    64
#define NPAD    1600   // padded xo width: cols 0..5 = head, 64..1599 = gates (g-6), rest zero
#define KA      512    // GEMM K = HDIM + FDIM (bias rows folded into cvec)
#define BH      (BATCH*HDIM)   // 98304

typedef __bf16 bf16x8 __attribute__((ext_vector_type(8)));
typedef float  f32x4  __attribute__((ext_vector_type(4)));

__device__ __forceinline__ float sigmoidf_(float x){ return 1.f/(1.f+__expf(-x)); }

// ---------------- init h, c, hb16 to zero ----------------
__global__ void init_state(float* __restrict__ hf, float* __restrict__ c, __bf16* __restrict__ hb){
    int i = blockIdx.x*256 + threadIdx.x;   // BH threads
    hf[i] = 0.f; c[i] = 0.f; hb[i] = (__bf16)0.f;
}

// ---------------- cast x (T*B*F fp32) -> bf16 ----------------
__global__ void cast_x(const float* __restrict__ x, __bf16* __restrict__ xb, int n){
    int i = (blockIdx.x*256 + threadIdx.x)*4;
    if (i < n){
        float4 v = *(const float4*)(x+i);
        xb[i+0]=(__bf16)v.x; xb[i+1]=(__bf16)v.y; xb[i+2]=(__bf16)v.z; xb[i+3]=(__bf16)v.w;
    }
}

// ---------------- pack [Wr(384 rows); Wk(128 rows)] -> Bp[k/8][NPAD][8] bf16, + cvec ----------------
__global__ void pack_w(const float* __restrict__ Wk, const float* __restrict__ bk,
                       const float* __restrict__ Wr, const float* __restrict__ br,
                       __bf16* __restrict__ Bp, float* __restrict__ cvec){
    int gid = blockIdx.x*256 + threadIdx.x;    // 64*1600 = 102400 threads
    int k8  = gid / NPAD;
    int col = gid - k8*NPAD;
    bool valid = (col < 6) || (col >= 64);
    int g = (col < 6) ? col : (col - 58);      // gates: col = g + 58  (g>=6)
    bf16x8 out;
    #pragma unroll
    for (int j=0;j<8;++j){
        int k = k8*8 + j;
        float v = 0.f;
        if (valid) v = (k < HDIM) ? Wr[k*GDIM + g] : Wk[(k-HDIM)*GDIM + g];
        out[j] = (__bf16)v;
    }
    *(bf16x8*)(Bp + (size_t)gid*8) = out;
    if (k8 == 0){
        float cv = 0.f;
        if (valid) cv = Wk[FDIM*GDIM + g] + bk[g] + Wr[HDIM*GDIM + g] + br[g];
        cvec[col] = cv;
    }
}

// ---------------- per-step GEMM: xo = [h | x_t] @ Bp + cvec  (256 x NPAD) ----------------
__global__ __launch_bounds__(256) void step_gemm(const __bf16* __restrict__ hb, const __bf16* __restrict__ xb,
                                                 const __bf16* __restrict__ Bp, const float* __restrict__ cvec,
                                                 float* __restrict__ xo, int t){
    int wave = threadIdx.x >> 6;
    int lane = threadIdx.x & 63;
    int nblk = blockIdx.x % 25;        // 25 * 64 cols = 1600
    int mblk = blockIdx.x / 25;        // 4 * 64 rows = 256
    int m0 = mblk*64 + wave*16;
    int n0 = nblk*64;
    int row = m0 + (lane & 15);
    int kh  = (lane >> 4) * 8;         // A-frag k offset within k-step
    f32x4 acc[4] = {};
    const __bf16* hrow = hb + (size_t)row*HDIM;
    const __bf16* xrow = xb + ((size_t)t*BATCH + row)*FDIM;
    // k-steps 0..11 : h part (K 0..383)
    #pragma unroll
    for (int ks=0; ks<12; ++ks){
        int k = ks*32 + kh;
        bf16x8 a = *(const bf16x8*)(hrow + k);
        const __bf16* bp = Bp + (((size_t)(k>>3))*NPAD + n0 + (lane & 15))*8;
        #pragma unroll
        for (int nt=0; nt<4; ++nt){
            bf16x8 bfrag = *(const bf16x8*)(bp + nt*16*8);
            acc[nt] = __builtin_amdgcn_mfma_f32_16x16x32_bf16(a, bfrag, acc[nt], 0,0,0);
        }
    }
    // k-steps 12..15 : x part (K 384..511)
    #pragma unroll
    for (int ks=12; ks<16; ++ks){
        int k = ks*32 + kh;
        bf16x8 a = *(const bf16x8*)(xrow + (k - HDIM));
        const __bf16* bp = Bp + (((size_t)(k>>3))*NPAD + n0 + (lane & 15))*8;
        #pragma unroll
        for (int nt=0; nt<4; ++nt){
            bf16x8 bfrag = *(const bf16x8*)(bp + nt*16*8);
            acc[nt] = __builtin_amdgcn_mfma_f32_16x16x32_bf16(a, bfrag, acc[nt], 0,0,0);
        }
    }
    // C/D layout: col = lane&15, row = (lane>>4)*4 + i
    int r0   = m0 + ((lane >> 4) << 2);
    int ccol = lane & 15;
    #pragma unroll
    for (int nt=0; nt<4; ++nt){
        int col = n0 + nt*16 + ccol;
        float cv = cvec[col];
        #pragma unroll
        for (int i=0;i<4;++i)
            xo[(size_t)(r0+i)*NPAD + col] = acc[nt][i] + cv;
    }
}

// ---------------- per-step gates: masks + LSTM update ----------------
__global__ void step_gates(const float* __restrict__ xo, float* __restrict__ c,
                           float* __restrict__ hf, __bf16* __restrict__ hb,
                           float* __restrict__ bufh, float* __restrict__ bufd, int t){
    int gid = blockIdx.x*256 + threadIdx.x;     // BH threads
    int b = gid / HDIM;
    int u = gid - b*HDIM;
    const float* xr = xo + (size_t)b*NPAD;
    // fm = cumsum(softmax(xo[:, :3]))
    float a0=xr[0], a1=xr[1], a2=xr[2];
    float m1 = fmaxf(fmaxf(a0,a1),a2);
    float e0=__expf(a0-m1), e1=__expf(a1-m1), e2=__expf(a2-m1);
    float inv = 1.f/(e0+e1+e2);
    float fm0 = e0*inv, fm1 = fm0 + e1*inv, fm2 = fm1 + e2*inv;
    // im = reverse-cumsum(softmax(xo[:, 3:6]))
    float b0=xr[3], b1=xr[4], b2=xr[5];
    float m2 = fmaxf(fmaxf(b0,b1),b2);
    float f0=__expf(b0-m2), f1=__expf(b1-m2), f2=__expf(b2-m2);
    float inv2 = 1.f/(f0+f1+f2);
    float im2 = f2*inv2, im1 = im2 + f1*inv2, im0 = im1 + f0*inv2;
    int l = u >> 7;    // u = l*128 + cc
    float fml = (l==0)?fm0:((l==1)?fm1:fm2);
    float iml = (l==0)?im0:((l==1)?im1:im2);
    float fg = sigmoidf_(xr[64 + u]);
    float ig = sigmoidf_(xr[64 + 384 + u]);
    float og = sigmoidf_(xr[64 + 768 + u]);
    float ci = tanhf   (xr[64 + 1152 + u]);
    float cold = c[gid];
    float ov = fml*iml;
    float cn = ov*(fg*cold + ig*ci) + (fml-ov)*cold + (iml-ov)*ci;
    float h  = og * tanhf(cn);
    c[gid] = cn; hf[gid] = h; hb[gid] = (__bf16)h;
    if (t >= T_STEPS - KWIN){
        int slot = t - (T_STEPS - KWIN);
        bufh[(size_t)slot*BH + gid] = h;
        if (u == 0) bufd[slot*BATCH + b] = 1.f - (fm0+fm1+fm2)*(1.f/3.f);
    }
}

// ---------------- finals ----------------
__global__ void final_locdis(const float* __restrict__ bufd, float* __restrict__ locdis){
    int b = threadIdx.x;   // 256
    float d[KWIN]; float cum = 0.f;
    #pragma unroll
    for (int k=0;k<KWIN;++k){ cum += bufd[k*BATCH + b]; d[k] = cum; }
    float m = d[0];
    #pragma unroll
    for (int k=1;k<KWIN;++k) m = fmaxf(m, d[k]);
    float s = 0.f;
    #pragma unroll
    for (int k=0;k<KWIN;++k){ d[k] = __expf(d[k]-m); s += d[k]; }
    float invs = 1.f/s;
    #pragma unroll
    for (int k=0;k<KWIN;++k) locdis[b*KWIN + k] = d[k]*invs;
}

__global__ void final_lh(const float* __restrict__ bufh, const float* __restrict__ locdis,
                         float* __restrict__ lh, float* __restrict__ mh){
    int gid = blockIdx.x*256 + threadIdx.x;    // BH
    int b = gid / HDIM;
    int i = gid - b*HDIM;
    float s = 0.f;
    #pragma unroll
    for (int k=0;k<KWIN;++k){
        float v = bufh[(size_t)k*BH + gid] * locdis[b*KWIN + k];
        lh[(size_t)b*(HDIM*KWIN) + i*KWIN + k] = v;
        s += v;
    }
    mh[gid] = s * (1.f/KWIN);
}

// conv[b,o] = dot(lh[b,:], Wc[o,:]) + bc[o]   (both rows 3840 contiguous); 32x32 tiles, LDS
__global__ __launch_bounds__(256) void final_conv(const float* __restrict__ lh, const float* __restrict__ Wc,
                                                  const float* __restrict__ bc, float* __restrict__ cvout){
    __shared__ float As[32*257];
    __shared__ float Bs[32*257];
    int tid = threadIdx.x;
    int bb = blockIdx.x / 12, ob = blockIdx.x % 12;   // 8 x 12 = 96 blocks
    int tx = tid & 15, ty = tid >> 4;
    float acc00=0.f, acc01=0.f, acc10=0.f, acc11=0.f;
    const int KD = HDIM*KWIN;   // 3840 = 15 * 256
    for (int ch=0; ch<15; ++ch){
        #pragma unroll
        for (int p=0;p<8;++p){
            int q   = tid + p*256;        // float4 index 0..2047
            int row = q >> 6;
            int c4  = q & 63;
            float4 va = *(const float4*)(lh + (size_t)(bb*32+row)*KD + ch*256 + c4*4);
            float4 vb = *(const float4*)(Wc + (size_t)(ob*32+row)*KD + ch*256 + c4*4);
            int o = row*257 + c4*4;
            As[o+0]=va.x; As[o+1]=va.y; As[o+2]=va.z; As[o+3]=va.w;
            Bs[o+0]=vb.x; Bs[o+1]=vb.y; Bs[o+2]=vb.z; Bs[o+3]=vb.w;
        }
        __syncthreads();
        for (int kk=0; kk<256; ++kk){
            float x0 = As[ty*257+kk],      x1 = As[(ty+16)*257+kk];
            float w0 = Bs[tx*257+kk],      w1 = Bs[(tx+16)*257+kk];
            acc00 += x0*w0; acc01 += x0*w1; acc10 += x1*w0; acc11 += x1*w1;
        }
        __syncthreads();
    }
    int r0 = bb*32+ty, r1 = r0+16, o0 = ob*32+tx, o1 = o0+16;
    cvout[(size_t)r0*HDIM + o0] = acc00 + bc[o0];
    cvout[(size_t)r0*HDIM + o1] = acc01 + bc[o1];
    cvout[(size_t)r1*HDIM + o0] = acc10 + bc[o0];
    cvout[(size_t)r1*HDIM + o1] = acc11 + bc[o1];
}

__global__ void final_th1(const float* __restrict__ mh, const float* __restrict__ Ws,
                          const float* __restrict__ bs, float* __restrict__ th1){
    int gid = blockIdx.x*256 + threadIdx.x;   // 256*64
    int b = gid >> 6, s = gid & 63;
    float acc = bs[s];
    const float* mr = mh + (size_t)b*HDIM;
    for (int i=0;i<HDIM;++i) acc += mr[i] * Ws[i*SDIM + s];
    th1[gid] = fmaxf(acc, 0.f);
}

__global__ void final_theme(const float* __restrict__ th1, const float* __restrict__ Wrs,
                            const float* __restrict__ brs, float* __restrict__ theme){
    int gid = blockIdx.x*256 + threadIdx.x;   // BH
    int b = gid / HDIM, o = gid - b*HDIM;
    float acc = brs[o];
    const float* tr = th1 + b*SDIM;
    for (int j=0;j<SDIM;++j) acc += tr[j] * Wrs[j*HDIM + o];
    theme[gid] = sigmoidf_(acc);
}

__global__ void final_out(const float* __restrict__ theme, const float* __restrict__ cvout,
                          const float* __restrict__ hf, const float* __restrict__ Wo,
                          const float* __restrict__ bo, float* __restrict__ out){
    int b = blockIdx.x, lane = threadIdx.x;   // 256 blocks x 64 threads
    float s = 0.f;
    for (int u=lane; u<HDIM; u+=64){
        float r = theme[(size_t)b*HDIM+u]*cvout[(size_t)b*HDIM+u] + hf[(size_t)b*HDIM+u];
        s += r * Wo[u];
    }
    #pragma unroll
    for (int off=32; off; off>>=1) s += __shfl_down(s, off);
    if (lane == 0) out[b] = sigmoidf_(s + bo[0]);
}

extern "C" void kernel_launch(void* const* d_in, const int* in_sizes, int n_in,
                              void* d_out, int out_size, void* d_ws, size_t ws_size,
                              hipStream_t stream){
    const float* x   = (const float*)d_in[0];
    const float* Wk  = (const float*)d_in[1];
    const float* bk  = (const float*)d_in[2];
    const float* Wr  = (const float*)d_in[3];
    const float* br  = (const float*)d_in[4];
    const float* Ws  = (const float*)d_in[5];
    const float* bs  = (const float*)d_in[6];
    const float* Wrs = (const float*)d_in[7];
    const float* brs = (const float*)d_in[8];
    const float* Wc  = (const float*)d_in[9];
    const float* bc  = (const float*)d_in[10];
    const float* Wo  = (const float*)d_in[11];
    const float* bo  = (const float*)d_in[12];
    float* out = (float*)d_out;

    char* w = (char*)d_ws;
    auto alloc = [&](size_t bytes)->char*{ char* p = w; w += (bytes + 255) & ~(size_t)255; return p; };
    __bf16* xb    = (__bf16*)alloc((size_t)T_STEPS*BATCH*FDIM*2);   // 16.8 MB
    __bf16* Bp    = (__bf16*)alloc((size_t)(KA/8)*NPAD*8*2);        // 1.64 MB
    float* cvec   = (float*) alloc(NPAD*4);
    float* hf     = (float*) alloc((size_t)BH*4);
    __bf16* hb    = (__bf16*)alloc((size_t)BH*2);
    float* c      = (float*) alloc((size_t)BH*4);
    float* xo     = (float*) alloc((size_t)BATCH*NPAD*4);
    float* bufh   = (float*) alloc((size_t)KWIN*BH*4);
    float* bufd   = (float*) alloc((size_t)KWIN*BATCH*4);
    float* locdis = (float*) alloc((size_t)BATCH*KWIN*4);
    float* lh     = (float*) alloc((size_t)BATCH*HDIM*KWIN*4);
    float* mh     = (float*) alloc((size_t)BH*4);
    float* th1    = (float*) alloc((size_t)BATCH*SDIM*4);
    float* theme  = (float*) alloc((size_t)BH*4);
    float* convb  = (float*) alloc((size_t)BH*4);

    init_state<<<dim3(BH/256), dim3(256), 0, stream>>>(hf, c, hb);
    cast_x<<<dim3((T_STEPS*BATCH*FDIM)/4/256), dim3(256), 0, stream>>>(x, xb, T_STEPS*BATCH*FDIM);
    pack_w<<<dim3((KA/8)*NPAD/256), dim3(256), 0, stream>>>(Wk, bk, Wr, br, Bp, cvec);

    for (int t=0; t<T_STEPS; ++t){
        step_gemm <<<dim3(100), dim3(256), 0, stream>>>(hb, xb, Bp, cvec, xo, t);
        step_gates<<<dim3(BH/256), dim3(256), 0, stream>>>(xo, c, hf, hb, bufh, bufd, t);
    }

    final_locdis<<<dim3(1),   dim3(256), 0, stream>>>(bufd, locdis);
    final_lh    <<<dim3(BH/256), dim3(256), 0, stream>>>(bufh, locdis, lh, mh);
    final_conv  <<<dim3(96),  dim3(256), 0, stream>>>(lh, Wc, bc, convb);
    final_th1   <<<dim3(BATCH*SDIM/256), dim3(256), 0, stream>>>(mh, Ws, bs, th1);
    final_theme <<<dim3(BH/256), dim3(256), 0, stream>>>(th1, Wrs, brs, theme);
    final_out   <<<dim3(BATCH), dim3(64), 0, stream>>>(theme, convb, hf, Wo, bo, out);
}